// Round 1
// baseline (812.138 us; speedup 1.0000x reference)
//
#include <hip/hip_runtime.h>

#define B_ 4
#define T_ 256
#define U_ 64
#define D_ 512    // ENC_DIM == PRED_DIM
#define W_LD 1024 // W leading dim (ENC_DIM+PRED_DIM)
#define V_ 2048   // VOCAB
#define MROWS 1280 // 1024 enc rows + 256 pred rows

typedef __attribute__((ext_vector_type(8))) __bf16 bf16x8;
typedef __attribute__((ext_vector_type(4))) float f32x4;

static __device__ inline bf16x8 load8_bf16(const float* __restrict__ p) {
    float4 a = *(const float4*)p;
    float4 b = *(const float4*)(p + 4);
    bf16x8 r;
    r[0] = (__bf16)a.x; r[1] = (__bf16)a.y; r[2] = (__bf16)a.z; r[3] = (__bf16)a.w;
    r[4] = (__bf16)b.x; r[5] = (__bf16)b.y; r[6] = (__bf16)b.z; r[7] = (__bf16)b.w;
    return r;
}

// Phase A: proj[m][v] = sum_k X[m][k] * Wpart[v][k]
//   rows 0..1023  : X = enc_out (b*T+t), Wpart = W[:, 0:512]
//   rows 1024..1279: X = pred_out (b*U+u), Wpart = W[:, 512:1024]
// grid: x = N-tile of 256 cols (8), y = M-tile of 16 rows (80). 4 waves/block,
// wave w covers cols [x*256 + w*64, +64) as 4 MFMA accumulators.
__global__ __launch_bounds__(256) void proj_gemm(
        const float* __restrict__ enc, const float* __restrict__ pred,
        const float* __restrict__ W, float* __restrict__ proj) {
    const int wave = threadIdx.x >> 6;
    const int lane = threadIdx.x & 63;
    const int quad = lane >> 4;     // 0..3
    const int l16  = lane & 15;
    const int mtile = blockIdx.y;   // 16 rows
    const int nbase = blockIdx.x * 256 + wave * 64;

    const int mrow = mtile * 16 + l16;           // row this lane's A-frag belongs to
    const float* arow;
    const float* wbase;
    if (mrow < 1024) { arow = enc  + (size_t)mrow * D_;          wbase = W; }
    else             { arow = pred + (size_t)(mrow - 1024) * D_; wbase = W + D_; }

    f32x4 acc[4];
    #pragma unroll
    for (int j = 0; j < 4; ++j) acc[j] = (f32x4){0.f, 0.f, 0.f, 0.f};

    #pragma unroll 4
    for (int ks = 0; ks < 16; ++ks) {           // K = 512 = 16 * 32
        const int k = ks * 32 + quad * 8;
        bf16x8 af = load8_bf16(arow + k);
        #pragma unroll
        for (int j = 0; j < 4; ++j) {
            const float* wp = wbase + (size_t)(nbase + j * 16 + l16) * W_LD + k;
            bf16x8 bf = load8_bf16(wp);
            acc[j] = __builtin_amdgcn_mfma_f32_16x16x32_bf16(af, bf, acc[j], 0, 0, 0);
        }
    }

    // C/D layout: col = lane&15, row = (lane>>4)*4 + reg
    const int mb = mtile * 16 + quad * 4;
    #pragma unroll
    for (int j = 0; j < 4; ++j) {
        const int v = nbase + j * 16 + l16;
        #pragma unroll
        for (int r = 0; r < 4; ++r)
            proj[(size_t)(mb + r) * V_ + v] = acc[j][r];
    }
}

// Phase B: out[b,t,u,v] = enc_proj[b,t,v] + pred_proj[b,u,v] + bias[v]
// One block per (b,t). Thread owns 8 consecutive v; enc_proj+bias in regs,
// reused across all 64 u. Writes: coalesced float4, 512 KB contiguous/block.
__global__ __launch_bounds__(256) void bcast_add(
        const float* __restrict__ proj, const float* __restrict__ bias,
        float* __restrict__ out) {
    const int row = blockIdx.x;      // b*T + t
    const int b   = row >> 8;
    const int v0  = threadIdx.x * 8;

    float4 e0 = *(const float4*)(proj + (size_t)row * V_ + v0);
    float4 e1 = *(const float4*)(proj + (size_t)row * V_ + v0 + 4);
    float4 c0 = *(const float4*)(bias + v0);
    float4 c1 = *(const float4*)(bias + v0 + 4);
    e0.x += c0.x; e0.y += c0.y; e0.z += c0.z; e0.w += c0.w;
    e1.x += c1.x; e1.y += c1.y; e1.z += c1.z; e1.w += c1.w;

    const float* prow = proj + (size_t)(1024 + b * U_) * V_;
    float* orow = out + (size_t)row * U_ * V_;

    #pragma unroll 4
    for (int u = 0; u < U_; ++u) {
        float4 p0 = *(const float4*)(prow + (size_t)u * V_ + v0);
        float4 p1 = *(const float4*)(prow + (size_t)u * V_ + v0 + 4);
        float4 o0 = make_float4(e0.x + p0.x, e0.y + p0.y, e0.z + p0.z, e0.w + p0.w);
        float4 o1 = make_float4(e1.x + p1.x, e1.y + p1.y, e1.z + p1.z, e1.w + p1.w);
        *(float4*)(orow + (size_t)u * V_ + v0)     = o0;
        *(float4*)(orow + (size_t)u * V_ + v0 + 4) = o1;
    }
}

extern "C" void kernel_launch(void* const* d_in, const int* in_sizes, int n_in,
                              void* d_out, int out_size, void* d_ws, size_t ws_size,
                              hipStream_t stream) {
    const float* enc  = (const float*)d_in[0];
    const float* pred = (const float*)d_in[1];
    const float* W    = (const float*)d_in[2];
    const float* bias = (const float*)d_in[3];
    float* out  = (float*)d_out;
    float* proj = (float*)d_ws;   // MROWS * V_ * 4 = 10.5 MB

    dim3 gA(V_ / 256, MROWS / 16);       // (8, 80)
    proj_gemm<<<gA, dim3(256), 0, stream>>>(enc, pred, W, proj);
    bcast_add<<<dim3(B_ * T_), dim3(256), 0, stream>>>(proj, bias, out);
}